// Round 3
// baseline (130.599 us; speedup 1.0000x reference)
//
#include <hip/hip_runtime.h>
#include <math.h>
#include <stdint.h>

#define LSEQ 256
#define HD 256

// ---------------- async global -> LDS (16B per lane, 1KB per wave-instr) ----
// Global source address is per-lane; LDS dest is wave-uniform base + lane*16.
__device__ __forceinline__ void glds16(const float* g, const float* l) {
    __builtin_amdgcn_global_load_lds(
        (const __attribute__((address_space(1))) void*)(uintptr_t)g,
        (__attribute__((address_space(3))) void*)(uint32_t)(uintptr_t)l,
        16, 0, 0);
}

// ---------------- Phase 1: projections + abs_pos fold ----------------
__global__ __launch_bounds__(256) void proj_kernel(
    const float* __restrict__ queries, const float* __restrict__ keys,
    const float* __restrict__ values,
    const float* __restrict__ apK, const float* __restrict__ apV,
    const float* __restrict__ Wq, const float* __restrict__ bq,
    const float* __restrict__ Wk, const float* __restrict__ bk,
    const float* __restrict__ Wv, const float* __restrict__ bv,
    float* __restrict__ Qo, float* __restrict__ Ko, float* __restrict__ Vo)
{
    const int R = 4;
    int tid = threadIdx.x;
    int row0 = blockIdx.x * R;

    float aq[R] = {0.f, 0.f, 0.f, 0.f};
    float ak[R] = {0.f, 0.f, 0.f, 0.f};
    float av[R] = {0.f, 0.f, 0.f, 0.f};

    const float* wq = Wq + tid * HD;
    const float* wk = Wk + tid * HD;
    const float* wv = Wv + tid * HD;

    #pragma unroll 2
    for (int i = 0; i < HD; i += 4) {
        float4 wq4 = *(const float4*)(wq + i);
        float4 wk4 = *(const float4*)(wk + i);
        float4 wv4 = *(const float4*)(wv + i);
        #pragma unroll
        for (int r = 0; r < R; ++r) {
            float4 xq = *(const float4*)(queries + (row0 + r) * HD + i);
            float4 xk = *(const float4*)(keys    + (row0 + r) * HD + i);
            float4 xv = *(const float4*)(values  + (row0 + r) * HD + i);
            aq[r] += xq.x * wq4.x + xq.y * wq4.y + xq.z * wq4.z + xq.w * wq4.w;
            ak[r] += xk.x * wk4.x + xk.y * wk4.y + xk.z * wk4.z + xk.w * wk4.w;
            av[r] += xv.x * wv4.x + xv.y * wv4.y + xv.z * wv4.z + xv.w * wv4.w;
        }
    }
    #pragma unroll
    for (int r = 0; r < R; ++r) {
        int idx = (row0 + r) * HD + tid;
        Qo[idx] = aq[r] + bq[tid];
        Ko[idx] = ak[r] + bk[tid] + apK[idx];
        Vo[idx] = av[r] + bv[tid] + apV[idx];
    }
}

// ---------------- Phase 2: fused scores + softmax + PV, LDS-staged ----------
// 512 threads = 8 waves, one block per (b,q). Chunks of 8 k-rows; wave w owns
// row (c*8+w). Double-buffered global_load_lds staging: in-flight bytes live
// in LDS, not VGPRs -> BW-bound instead of latency-bound.
__global__ __launch_bounds__(512, 6) void attn_kernel(
    const float* __restrict__ Q, const float* __restrict__ Keff,
    const float* __restrict__ Veff,
    const float* __restrict__ tK, const float* __restrict__ tV,
    const int* __restrict__ tmask, float* __restrict__ out)
{
    __shared__ float stage[2][16][HD];   // [buf][0..7 tK/tV rows, 8..15 Keff/Veff rows][256]
    __shared__ float sc[4][260];         // per-head attn weights (padded)
    __shared__ float outp[8][256];

    int bid = blockIdx.x;
    int b = bid >> 8;
    int ii = bid & 255;
    int q = (ii & 1) ? (255 - (ii >> 1)) : (ii >> 1);   // pair light/heavy rows
    int bq = (b << 8) | q;

    int tid = threadIdx.x;
    int w = tid >> 6;
    int lane = tid & 63;
    int head = lane >> 4;
    int le4 = lane * 4;

    bool masked = tmask[bq] != 0;   // whole row NEG -> exactly uniform attn

    const float* tKr = tK + (size_t)bq * (LSEQ * HD);
    const float* tVr = tV + (size_t)bq * (LSEQ * HD);
    const float* Kb = Keff + b * (LSEQ * HD);
    const float* Vb = Veff + b * (LSEQ * HD);

    if (!masked) {
        float4 q4 = *(const float4*)(Q + bq * HD + le4);
        int nk = q + 1;                 // causal: k <= q only (rest exact 0)
        int nch = (nk + 7) >> 3;
        // prologue: chunk 0 -> buf 0
        {
            int k = w;
            if (k < nk) {
                glds16(tKr + k * HD + le4, &stage[0][w][0]);
                glds16(Kb  + k * HD + le4, &stage[0][8 + w][0]);
            }
        }
        for (int c = 0; c < nch; ++c) {
            int k2 = (c + 1) * 8 + w;
            if (k2 < nk) {              // prefetch chunk c+1
                glds16(tKr + k2 * HD + le4, &stage[(c + 1) & 1][w][0]);
                glds16(Kb  + k2 * HD + le4, &stage[(c + 1) & 1][8 + w][0]);
            }
            __syncthreads();            // chunk c complete + visible
            int k = c * 8 + w;
            if (k < nk) {
                float4 t4 = *(const float4*)&stage[c & 1][w][le4];
                float4 k4 = *(const float4*)&stage[c & 1][8 + w][le4];
                float s = q4.x * (t4.x + k4.x) + q4.y * (t4.y + k4.y)
                        + q4.z * (t4.z + k4.z) + q4.w * (t4.w + k4.w);
                s += __shfl_xor(s, 1);
                s += __shfl_xor(s, 2);
                s += __shfl_xor(s, 4);
                s += __shfl_xor(s, 8);
                if ((lane & 15) == 0) sc[head][k] = s * 0.125f;  // /sqrt(64)
            }
            __syncthreads();            // consumed: buffer may be overwritten
        }
        // softmax: wave w (<4) handles head w over k=0..255 (k>q -> -inf)
        if (w < 4) {
            int k0 = lane * 4;
            float4 v = *(const float4*)(&sc[w][k0]);
            float x0 = (k0 + 0 <= q) ? v.x : -INFINITY;
            float x1 = (k0 + 1 <= q) ? v.y : -INFINITY;
            float x2 = (k0 + 2 <= q) ? v.z : -INFINITY;
            float x3 = (k0 + 3 <= q) ? v.w : -INFINITY;
            float m = fmaxf(fmaxf(x0, x1), fmaxf(x2, x3));
            #pragma unroll
            for (int off = 32; off >= 1; off >>= 1)
                m = fmaxf(m, __shfl_xor(m, off));
            float e0 = __expf(x0 - m);
            float e1 = __expf(x1 - m);
            float e2 = __expf(x2 - m);
            float e3 = __expf(x3 - m);
            float ssum = e0 + e1 + e2 + e3;
            #pragma unroll
            for (int off = 32; off >= 1; off >>= 1)
                ssum += __shfl_xor(ssum, off);
            float inv = 1.0f / ssum;
            *(float4*)(&sc[w][k0]) = make_float4(e0 * inv, e1 * inv, e2 * inv, e3 * inv);
        }
        __syncthreads();
    }

    // PV: out[t] = sum_k a[head][k] * (tV[b,q,k,t] + Veff[b,k,t])
    float4 acc = make_float4(0.f, 0.f, 0.f, 0.f);
    int kmax = masked ? (LSEQ - 1) : q;
    int nk2 = kmax + 1;
    int nch2 = (nk2 + 7) >> 3;
    const float uw = 1.0f / 256.0f;     // uniform weights for masked rows
    {
        int k = w;
        if (k < nk2) {
            glds16(tVr + k * HD + le4, &stage[0][w][0]);
            glds16(Vb  + k * HD + le4, &stage[0][8 + w][0]);
        }
    }
    for (int c = 0; c < nch2; ++c) {
        int k2 = (c + 1) * 8 + w;
        if (k2 < nk2) {
            glds16(tVr + k2 * HD + le4, &stage[(c + 1) & 1][w][0]);
            glds16(Vb  + k2 * HD + le4, &stage[(c + 1) & 1][8 + w][0]);
        }
        __syncthreads();
        int k = c * 8 + w;
        if (k < nk2) {
            float a = masked ? uw : sc[head][k];
            float4 t4 = *(const float4*)&stage[c & 1][w][le4];
            float4 v4 = *(const float4*)&stage[c & 1][8 + w][le4];
            acc.x += a * (t4.x + v4.x);
            acc.y += a * (t4.y + v4.y);
            acc.z += a * (t4.z + v4.z);
            acc.w += a * (t4.w + v4.w);
        }
        __syncthreads();
    }
    *(float4*)(&outp[w][le4]) = acc;
    __syncthreads();
    if (tid < 256) {
        float o = 0.f;
        #pragma unroll
        for (int p = 0; p < 8; ++p) o += outp[p][tid];
        out[bq * HD + tid] = o;
    }
}

extern "C" void kernel_launch(void* const* d_in, const int* in_sizes, int n_in,
                              void* d_out, int out_size, void* d_ws, size_t ws_size,
                              hipStream_t stream) {
    const float* queries = (const float*)d_in[0];
    const float* keys    = (const float*)d_in[1];
    const float* values  = (const float*)d_in[2];
    const float* tK      = (const float*)d_in[3];
    const float* tV      = (const float*)d_in[4];
    const float* apK     = (const float*)d_in[5];
    const float* apV     = (const float*)d_in[6];
    const int*   tmask   = (const int*)d_in[7];
    // d_in[8] future_time_mask: analytic (k > q), never read
    const float* Wq = (const float*)d_in[9];
    const float* bq = (const float*)d_in[10];
    const float* Wk = (const float*)d_in[11];
    const float* bk = (const float*)d_in[12];
    const float* Wv = (const float*)d_in[13];
    const float* bv = (const float*)d_in[14];

    float* ws = (float*)d_ws;
    float* Qo = ws;                 // [1024][256]
    float* Ko = ws + 262144;        // Keff = K + bk + pK
    float* Vo = ws + 524288;        // Veff = V + bv + pV
    float* out = (float*)d_out;

    proj_kernel<<<256, 256, 0, stream>>>(queries, keys, values, apK, apV,
                                         Wq, bq, Wk, bk, Wv, bv, Qo, Ko, Vo);
    attn_kernel<<<1024, 512, 0, stream>>>(Qo, Ko, Vo, tK, tV, tmask, out);
}

// Round 4
// 113.488 us; speedup vs baseline: 1.1508x; 1.1508x over previous
//
#include <hip/hip_runtime.h>
#include <math.h>
#include <stdint.h>

#define LSEQ 256
#define HD 256

__device__ __forceinline__ float dot4(float4 a, float4 b) {
    return a.x * b.x + a.y * b.y + a.z * b.z + a.w * b.w;
}
__device__ __forceinline__ float4 add4(float4 a, float4 b) {
    return make_float4(a.x + b.x, a.y + b.y, a.z + b.z, a.w + b.w);
}

// ---------------- 1. projections + abs_pos fold ----------------
__global__ __launch_bounds__(256) void proj_kernel(
    const float* __restrict__ queries, const float* __restrict__ keys,
    const float* __restrict__ values,
    const float* __restrict__ apK, const float* __restrict__ apV,
    const float* __restrict__ Wq, const float* __restrict__ bq,
    const float* __restrict__ Wk, const float* __restrict__ bk,
    const float* __restrict__ Wv, const float* __restrict__ bv,
    float* __restrict__ Qo, float* __restrict__ Ko, float* __restrict__ Vo)
{
    const int R = 4;
    int tid = threadIdx.x;
    int row0 = blockIdx.x * R;

    float aq[R] = {0.f, 0.f, 0.f, 0.f};
    float ak[R] = {0.f, 0.f, 0.f, 0.f};
    float av[R] = {0.f, 0.f, 0.f, 0.f};

    const float* wq = Wq + tid * HD;
    const float* wk = Wk + tid * HD;
    const float* wv = Wv + tid * HD;

    #pragma unroll 2
    for (int i = 0; i < HD; i += 4) {
        float4 wq4 = *(const float4*)(wq + i);
        float4 wk4 = *(const float4*)(wk + i);
        float4 wv4 = *(const float4*)(wv + i);
        #pragma unroll
        for (int r = 0; r < R; ++r) {
            float4 xq = *(const float4*)(queries + (row0 + r) * HD + i);
            float4 xk = *(const float4*)(keys    + (row0 + r) * HD + i);
            float4 xv = *(const float4*)(values  + (row0 + r) * HD + i);
            aq[r] += dot4(xq, wq4);
            ak[r] += dot4(xk, wk4);
            av[r] += dot4(xv, wv4);
        }
    }
    #pragma unroll
    for (int r = 0; r < R; ++r) {
        int idx = (row0 + r) * HD + tid;
        Qo[idx] = aq[r] + bq[tid];
        Ko[idx] = ak[r] + bk[tid] + apK[idx];
        Vo[idx] = av[r] + bv[tid] + apV[idx];
    }
}

// ---------------- 2. scores (streaming, no barriers) ----------------
// grid = 1024 bq * 8 chunks of 32 k. Block 256 thr = 4 waves; wave v owns
// k = 32c + v + 4j. 4-row batches: 8 KB in flight per wave.
__global__ __launch_bounds__(256, 4) void scores_kernel(
    const float* __restrict__ Q, const float* __restrict__ Keff,
    const float* __restrict__ tK, const int* __restrict__ tmask,
    float* __restrict__ sc_out)
{
    int bid = blockIdx.x;
    int bq = bid >> 3;
    int c = bid & 7;
    int q = bq & 255;
    int b = bq >> 8;
    int k0c = c << 5;
    if (k0c > q || tmask[bq]) return;   // causal / masked-row: exact zeros later

    int tid = threadIdx.x;
    int v = tid >> 6;
    int lane = tid & 63;
    int head = lane >> 4;
    int le4 = lane * 4;

    const float* tKr = tK + (size_t)bq * (LSEQ * HD);
    const float* Kb  = Keff + b * (LSEQ * HD);
    float4 q4 = *(const float4*)(Q + bq * HD + le4);
    int kend = min(k0c + 32, q + 1);
    float* scrow = sc_out + (size_t)(bq * 4 + head) * LSEQ;

    int k = k0c + v;
    for (; k + 12 < kend; k += 16) {
        float4 t0 = *(const float4*)(tKr + (k     ) * HD + le4);
        float4 t1 = *(const float4*)(tKr + (k +  4) * HD + le4);
        float4 t2 = *(const float4*)(tKr + (k +  8) * HD + le4);
        float4 t3 = *(const float4*)(tKr + (k + 12) * HD + le4);
        float4 c0 = *(const float4*)(Kb  + (k     ) * HD + le4);
        float4 c1 = *(const float4*)(Kb  + (k +  4) * HD + le4);
        float4 c2 = *(const float4*)(Kb  + (k +  8) * HD + le4);
        float4 c3 = *(const float4*)(Kb  + (k + 12) * HD + le4);
        float s0 = dot4(q4, add4(t0, c0));
        float s1 = dot4(q4, add4(t1, c1));
        float s2 = dot4(q4, add4(t2, c2));
        float s3 = dot4(q4, add4(t3, c3));
        #pragma unroll
        for (int off = 1; off <= 8; off <<= 1) {
            s0 += __shfl_xor(s0, off);
            s1 += __shfl_xor(s1, off);
            s2 += __shfl_xor(s2, off);
            s3 += __shfl_xor(s3, off);
        }
        if ((lane & 15) == 0) {
            scrow[k     ] = s0 * 0.125f;   // /sqrt(64)
            scrow[k +  4] = s1 * 0.125f;
            scrow[k +  8] = s2 * 0.125f;
            scrow[k + 12] = s3 * 0.125f;
        }
    }
    for (; k < kend; k += 4) {
        float4 t0 = *(const float4*)(tKr + k * HD + le4);
        float4 c0 = *(const float4*)(Kb  + k * HD + le4);
        float s0 = dot4(q4, add4(t0, c0));
        #pragma unroll
        for (int off = 1; off <= 8; off <<= 1)
            s0 += __shfl_xor(s0, off);
        if ((lane & 15) == 0) scrow[k] = s0 * 0.125f;
    }
}

// ---------------- 3. softmax (per (bq, head) row) ----------------
__global__ __launch_bounds__(256, 4) void softmax_kernel(
    float* __restrict__ sc, const int* __restrict__ tmask)
{
    int bq = blockIdx.x;
    if (tmask[bq]) return;              // masked rows handled analytically in PV
    int q = bq & 255;
    int tid = threadIdx.x;
    int w = tid >> 6;
    int lane = tid & 63;
    float* row = sc + (size_t)(bq * 4 + w) * LSEQ;
    int k0 = lane * 4;
    float4 vv = *(const float4*)(row + k0);
    float x0 = (k0 + 0 <= q) ? vv.x : -INFINITY;
    float x1 = (k0 + 1 <= q) ? vv.y : -INFINITY;
    float x2 = (k0 + 2 <= q) ? vv.z : -INFINITY;
    float x3 = (k0 + 3 <= q) ? vv.w : -INFINITY;
    float m = fmaxf(fmaxf(x0, x1), fmaxf(x2, x3));
    #pragma unroll
    for (int off = 32; off >= 1; off >>= 1)
        m = fmaxf(m, __shfl_xor(m, off));
    float e0 = __expf(x0 - m);
    float e1 = __expf(x1 - m);
    float e2 = __expf(x2 - m);
    float e3 = __expf(x3 - m);
    float ssum = e0 + e1 + e2 + e3;
    #pragma unroll
    for (int off = 32; off >= 1; off >>= 1)
        ssum += __shfl_xor(ssum, off);
    float inv = 1.0f / ssum;
    *(float4*)(row + k0) = make_float4(e0 * inv, e1 * inv, e2 * inv, e3 * inv);
}

// ---------------- 4. PV (streaming, one barrier) ----------------
// grid = 1024 bq * 4 chunks of 64 k. Wave v owns k = 64c + v + 4j; 4-row
// batches. Writes per-chunk partial sums; unvisited chunks stay unwritten
// (reduce kernel recomputes validity analytically).
__global__ __launch_bounds__(256, 4) void pv_kernel(
    const float* __restrict__ Veff, const float* __restrict__ tV,
    const float* __restrict__ attn, const int* __restrict__ tmask,
    float* __restrict__ part)
{
    __shared__ float outp[4][256];

    int bid = blockIdx.x;
    int bq = bid >> 2;
    int c = bid & 3;
    int q = bq & 255;
    int b = bq >> 8;
    bool masked = tmask[bq] != 0;       // whole row NEG -> exactly uniform attn
    int kstart = c << 6;
    if (!masked && kstart > q) return;
    int kend = min(kstart + 64, masked ? LSEQ : q + 1);

    int tid = threadIdx.x;
    int v = tid >> 6;
    int lane = tid & 63;
    int head = lane >> 4;
    int le4 = lane * 4;

    const float* tVr = tV + (size_t)bq * (LSEQ * HD);
    const float* Vb  = Veff + b * (LSEQ * HD);
    const float* arow = attn + (size_t)(bq * 4 + head) * LSEQ;
    const float uw = 1.0f / 256.0f;

    float4 acc = make_float4(0.f, 0.f, 0.f, 0.f);
    int k = kstart + v;
    for (; k + 12 < kend; k += 16) {
        float4 t0 = *(const float4*)(tVr + (k     ) * HD + le4);
        float4 t1 = *(const float4*)(tVr + (k +  4) * HD + le4);
        float4 t2 = *(const float4*)(tVr + (k +  8) * HD + le4);
        float4 t3 = *(const float4*)(tVr + (k + 12) * HD + le4);
        float4 v0 = *(const float4*)(Vb  + (k     ) * HD + le4);
        float4 v1 = *(const float4*)(Vb  + (k +  4) * HD + le4);
        float4 v2 = *(const float4*)(Vb  + (k +  8) * HD + le4);
        float4 v3 = *(const float4*)(Vb  + (k + 12) * HD + le4);
        float a0 = masked ? uw : arow[k     ];
        float a1 = masked ? uw : arow[k +  4];
        float a2 = masked ? uw : arow[k +  8];
        float a3 = masked ? uw : arow[k + 12];
        acc.x += a0 * (t0.x + v0.x) + a1 * (t1.x + v1.x)
               + a2 * (t2.x + v2.x) + a3 * (t3.x + v3.x);
        acc.y += a0 * (t0.y + v0.y) + a1 * (t1.y + v1.y)
               + a2 * (t2.y + v2.y) + a3 * (t3.y + v3.y);
        acc.z += a0 * (t0.z + v0.z) + a1 * (t1.z + v1.z)
               + a2 * (t2.z + v2.z) + a3 * (t3.z + v3.z);
        acc.w += a0 * (t0.w + v0.w) + a1 * (t1.w + v1.w)
               + a2 * (t2.w + v2.w) + a3 * (t3.w + v3.w);
    }
    for (; k < kend; k += 4) {
        float4 t0 = *(const float4*)(tVr + k * HD + le4);
        float4 v0 = *(const float4*)(Vb  + k * HD + le4);
        float a0 = masked ? uw : arow[k];
        acc.x += a0 * (t0.x + v0.x);
        acc.y += a0 * (t0.y + v0.y);
        acc.z += a0 * (t0.z + v0.z);
        acc.w += a0 * (t0.w + v0.w);
    }
    *(float4*)(&outp[v][le4]) = acc;
    __syncthreads();
    float o = outp[0][tid] + outp[1][tid] + outp[2][tid] + outp[3][tid];
    part[((size_t)((c << 10) | bq)) * HD + tid] = o;
}

// ---------------- 5. reduce partials -> output ----------------
__global__ __launch_bounds__(256) void reduce_kernel(
    const float* __restrict__ part, const int* __restrict__ tmask,
    float* __restrict__ out)
{
    int bq = blockIdx.x;
    int q = bq & 255;
    int tid = threadIdx.x;
    int nch = tmask[bq] ? 4 : ((q >> 6) + 1);   // analytically valid chunks
    float o = 0.f;
    for (int c = 0; c < nch; ++c)
        o += part[((size_t)((c << 10) | bq)) * HD + tid];
    out[(size_t)bq * HD + tid] = o;
}

extern "C" void kernel_launch(void* const* d_in, const int* in_sizes, int n_in,
                              void* d_out, int out_size, void* d_ws, size_t ws_size,
                              hipStream_t stream) {
    const float* queries = (const float*)d_in[0];
    const float* keys    = (const float*)d_in[1];
    const float* values  = (const float*)d_in[2];
    const float* tK      = (const float*)d_in[3];
    const float* tV      = (const float*)d_in[4];
    const float* apK     = (const float*)d_in[5];
    const float* apV     = (const float*)d_in[6];
    const int*   tmask   = (const int*)d_in[7];
    // d_in[8] future_time_mask: analytic (k > q), never read
    const float* Wq = (const float*)d_in[9];
    const float* bq = (const float*)d_in[10];
    const float* Wk = (const float*)d_in[11];
    const float* bk = (const float*)d_in[12];
    const float* Wv = (const float*)d_in[13];
    const float* bv = (const float*)d_in[14];

    float* ws = (float*)d_ws;
    float* Qo     = ws;                     // [1024][256]
    float* Ko     = ws + 262144;            // Keff = K + bk + pK
    float* Vo     = ws + 524288;            // Veff = V + bv + pV
    float* scores = ws + 786432;            // [1024*4][256]
    float* partb  = ws + 1835008;           // [4][1024][256]
    float* out = (float*)d_out;

    proj_kernel<<<256, 256, 0, stream>>>(queries, keys, values, apK, apV,
                                         Wq, bq, Wk, bk, Wv, bv, Qo, Ko, Vo);
    scores_kernel<<<8192, 256, 0, stream>>>(Qo, Ko, tK, tmask, scores);
    softmax_kernel<<<1024, 256, 0, stream>>>(scores, tmask);
    pv_kernel<<<4096, 256, 0, stream>>>(Vo, tV, scores, tmask, partb);
    reduce_kernel<<<1024, 256, 0, stream>>>(partb, tmask, out);
}

// Round 6
// 108.556 us; speedup vs baseline: 1.2030x; 1.0454x over previous
//
#include <hip/hip_runtime.h>
#include <math.h>
#include <stdint.h>

#define LSEQ 256
#define HD 256

typedef float floatx4 __attribute__((ext_vector_type(4)));

__device__ __forceinline__ float dot4(float4 a, float4 b) {
    return a.x * b.x + a.y * b.y + a.z * b.z + a.w * b.w;
}
__device__ __forceinline__ float4 add4(float4 a, float4 b) {
    return make_float4(a.x + b.x, a.y + b.y, a.z + b.z, a.w + b.w);
}
// non-temporal load: stream data, don't evict hot L2 lines
__device__ __forceinline__ float4 ldnt4(const float* p) {
    floatx4 r = __builtin_nontemporal_load((const floatx4*)p);
    return make_float4(r.x, r.y, r.z, r.w);
}

// ---------------- 1. projections + abs_pos fold ----------------
__global__ __launch_bounds__(256) void proj_kernel(
    const float* __restrict__ queries, const float* __restrict__ keys,
    const float* __restrict__ values,
    const float* __restrict__ apK, const float* __restrict__ apV,
    const float* __restrict__ Wq, const float* __restrict__ bq,
    const float* __restrict__ Wk, const float* __restrict__ bk,
    const float* __restrict__ Wv, const float* __restrict__ bv,
    float* __restrict__ Qo, float* __restrict__ Ko, float* __restrict__ Vo)
{
    const int R = 4;
    int tid = threadIdx.x;
    int row0 = blockIdx.x * R;

    float aq[R] = {0.f, 0.f, 0.f, 0.f};
    float ak[R] = {0.f, 0.f, 0.f, 0.f};
    float av[R] = {0.f, 0.f, 0.f, 0.f};

    const float* wq = Wq + tid * HD;
    const float* wk = Wk + tid * HD;
    const float* wv = Wv + tid * HD;

    #pragma unroll 2
    for (int i = 0; i < HD; i += 4) {
        float4 wq4 = *(const float4*)(wq + i);
        float4 wk4 = *(const float4*)(wk + i);
        float4 wv4 = *(const float4*)(wv + i);
        #pragma unroll
        for (int r = 0; r < R; ++r) {
            float4 xq = *(const float4*)(queries + (row0 + r) * HD + i);
            float4 xk = *(const float4*)(keys    + (row0 + r) * HD + i);
            float4 xv = *(const float4*)(values  + (row0 + r) * HD + i);
            aq[r] += dot4(xq, wq4);
            ak[r] += dot4(xk, wk4);
            av[r] += dot4(xv, wv4);
        }
    }
    #pragma unroll
    for (int r = 0; r < R; ++r) {
        int idx = (row0 + r) * HD + tid;
        Qo[idx] = aq[r] + bq[tid];
        Ko[idx] = ak[r] + bk[tid] + apK[idx];
        Vo[idx] = av[r] + bv[tid] + apV[idx];
    }
}

// ---------------- 2. scores ----------------
// grid = 1024 bq * 4 chunks of 64 k. Wave v owns the CONTIGUOUS run
// [c*64 + v*16, +16): each wave is a sequential 16KB DRAM stream, read in
// 4KB-contiguous batches of 4 rows.
__global__ __launch_bounds__(256) void scores_kernel(
    const float* __restrict__ Q, const float* __restrict__ Keff,
    const float* __restrict__ tK, const int* __restrict__ tmask,
    float* __restrict__ sc_out)
{
    int bid = blockIdx.x;
    int bq = bid >> 2;
    int c = bid & 3;
    int q = bq & 255;
    int b = bq >> 8;
    int k0c = c << 6;
    if (k0c > q || tmask[bq]) return;   // causal / masked-row: handled later

    int tid = threadIdx.x;
    int v = tid >> 6;
    int lane = tid & 63;
    int head = lane >> 4;
    int le4 = lane * 4;

    const float* tKr = tK + (size_t)bq * (LSEQ * HD);
    const float* Kb  = Keff + b * (LSEQ * HD);
    float4 q4 = *(const float4*)(Q + bq * HD + le4);
    float* scrow = sc_out + (size_t)(bq * 4 + head) * LSEQ;

    int r0 = k0c + v * 16;
    int rend = min(r0 + 16, q + 1);

    int k = r0;
    for (; k + 3 < rend; k += 4) {
        float4 t0 = ldnt4(tKr + (k    ) * HD + le4);
        float4 t1 = ldnt4(tKr + (k + 1) * HD + le4);
        float4 t2 = ldnt4(tKr + (k + 2) * HD + le4);
        float4 t3 = ldnt4(tKr + (k + 3) * HD + le4);
        float4 c0 = *(const float4*)(Kb + (k    ) * HD + le4);
        float4 c1 = *(const float4*)(Kb + (k + 1) * HD + le4);
        float4 c2 = *(const float4*)(Kb + (k + 2) * HD + le4);
        float4 c3 = *(const float4*)(Kb + (k + 3) * HD + le4);
        float s0 = dot4(q4, add4(t0, c0));
        float s1 = dot4(q4, add4(t1, c1));
        float s2 = dot4(q4, add4(t2, c2));
        float s3 = dot4(q4, add4(t3, c3));
        #pragma unroll
        for (int off = 1; off <= 8; off <<= 1) {
            s0 += __shfl_xor(s0, off);
            s1 += __shfl_xor(s1, off);
            s2 += __shfl_xor(s2, off);
            s3 += __shfl_xor(s3, off);
        }
        if ((lane & 15) == 0)
            *(float4*)(scrow + k) = make_float4(s0 * 0.125f, s1 * 0.125f,
                                                s2 * 0.125f, s3 * 0.125f);
    }
    for (; k < rend; ++k) {
        float4 t0 = ldnt4(tKr + k * HD + le4);
        float4 c0 = *(const float4*)(Kb + k * HD + le4);
        float s0 = dot4(q4, add4(t0, c0));
        #pragma unroll
        for (int off = 1; off <= 8; off <<= 1)
            s0 += __shfl_xor(s0, off);
        if ((lane & 15) == 0) scrow[k] = s0 * 0.125f;
    }
}

// ---------------- 3. softmax (per (bq, head) row) ----------------
__global__ __launch_bounds__(256) void softmax_kernel(
    float* __restrict__ sc, const int* __restrict__ tmask)
{
    int bq = blockIdx.x;
    if (tmask[bq]) return;              // masked rows handled analytically in PV
    int q = bq & 255;
    int tid = threadIdx.x;
    int w = tid >> 6;
    int lane = tid & 63;
    float* row = sc + (size_t)(bq * 4 + w) * LSEQ;
    int k0 = lane * 4;
    float4 vv = *(const float4*)(row + k0);
    float x0 = (k0 + 0 <= q) ? vv.x : -INFINITY;
    float x1 = (k0 + 1 <= q) ? vv.y : -INFINITY;
    float x2 = (k0 + 2 <= q) ? vv.z : -INFINITY;
    float x3 = (k0 + 3 <= q) ? vv.w : -INFINITY;
    float m = fmaxf(fmaxf(x0, x1), fmaxf(x2, x3));
    #pragma unroll
    for (int off = 32; off >= 1; off >>= 1)
        m = fmaxf(m, __shfl_xor(m, off));
    float e0 = __expf(x0 - m);
    float e1 = __expf(x1 - m);
    float e2 = __expf(x2 - m);
    float e3 = __expf(x3 - m);
    float ssum = e0 + e1 + e2 + e3;
    #pragma unroll
    for (int off = 32; off >= 1; off >>= 1)
        ssum += __shfl_xor(ssum, off);
    float inv = 1.0f / ssum;
    *(float4*)(row + k0) = make_float4(e0 * inv, e1 * inv, e2 * inv, e3 * inv);
}

// ---------------- 4. PV ----------------
// grid = 1024 bq * 4 chunks of 64 k. Wave v owns contiguous run
// [c*64 + v*16, +16) -> sequential DRAM stream per wave.
__global__ __launch_bounds__(256) void pv_kernel(
    const float* __restrict__ Veff, const float* __restrict__ tV,
    const float* __restrict__ attn, const int* __restrict__ tmask,
    float* __restrict__ part)
{
    __shared__ float outp[4][256];

    int bid = blockIdx.x;
    int bq = bid >> 2;
    int c = bid & 3;
    int q = bq & 255;
    int b = bq >> 8;
    bool masked = tmask[bq] != 0;       // whole row NEG -> exactly uniform attn
    int kstart = c << 6;
    if (!masked && kstart > q) return;
    int kendc = min(kstart + 64, masked ? LSEQ : q + 1);

    int tid = threadIdx.x;
    int v = tid >> 6;
    int lane = tid & 63;
    int head = lane >> 4;
    int le4 = lane * 4;

    const float* tVr = tV + (size_t)bq * (LSEQ * HD);
    const float* Vb  = Veff + b * (LSEQ * HD);
    const float* arow = attn + (size_t)(bq * 4 + head) * LSEQ;
    const float uw = 1.0f / 256.0f;

    int r0 = kstart + v * 16;
    int rend = min(r0 + 16, kendc);

    float4 acc = make_float4(0.f, 0.f, 0.f, 0.f);
    int k = r0;
    for (; k + 3 < rend; k += 4) {
        float4 t0 = ldnt4(tVr + (k    ) * HD + le4);
        float4 t1 = ldnt4(tVr + (k + 1) * HD + le4);
        float4 t2 = ldnt4(tVr + (k + 2) * HD + le4);
        float4 t3 = ldnt4(tVr + (k + 3) * HD + le4);
        float4 v0 = *(const float4*)(Vb + (k    ) * HD + le4);
        float4 v1 = *(const float4*)(Vb + (k + 1) * HD + le4);
        float4 v2 = *(const float4*)(Vb + (k + 2) * HD + le4);
        float4 v3 = *(const float4*)(Vb + (k + 3) * HD + le4);
        float4 a4;
        if (masked) a4 = make_float4(uw, uw, uw, uw);
        else        a4 = *(const float4*)(arow + k);
        acc.x += a4.x * (t0.x + v0.x) + a4.y * (t1.x + v1.x)
               + a4.z * (t2.x + v2.x) + a4.w * (t3.x + v3.x);
        acc.y += a4.x * (t0.y + v0.y) + a4.y * (t1.y + v1.y)
               + a4.z * (t2.y + v2.y) + a4.w * (t3.y + v3.y);
        acc.z += a4.x * (t0.z + v0.z) + a4.y * (t1.z + v1.z)
               + a4.z * (t2.z + v2.z) + a4.w * (t3.z + v3.z);
        acc.w += a4.x * (t0.w + v0.w) + a4.y * (t1.w + v1.w)
               + a4.z * (t2.w + v2.w) + a4.w * (t3.w + v3.w);
    }
    for (; k < rend; ++k) {
        float4 t0 = ldnt4(tVr + k * HD + le4);
        float4 v0 = *(const float4*)(Vb + k * HD + le4);
        float a0 = masked ? uw : arow[k];
        acc.x += a0 * (t0.x + v0.x);
        acc.y += a0 * (t0.y + v0.y);
        acc.z += a0 * (t0.z + v0.z);
        acc.w += a0 * (t0.w + v0.w);
    }
    *(float4*)(&outp[v][le4]) = acc;
    __syncthreads();
    float o = outp[0][tid] + outp[1][tid] + outp[2][tid] + outp[3][tid];
    part[((size_t)((c << 10) | bq)) * HD + tid] = o;
}

// ---------------- 5. reduce partials -> output ----------------
__global__ __launch_bounds__(256) void reduce_kernel(
    const float* __restrict__ part, const int* __restrict__ tmask,
    float* __restrict__ out)
{
    int bq = blockIdx.x;
    int q = bq & 255;
    int tid = threadIdx.x;
    int nch = tmask[bq] ? 4 : ((q >> 6) + 1);   // analytically valid chunks
    float o = 0.f;
    for (int c = 0; c < nch; ++c)
        o += part[((size_t)((c << 10) | bq)) * HD + tid];
    out[(size_t)bq * HD + tid] = o;
}

extern "C" void kernel_launch(void* const* d_in, const int* in_sizes, int n_in,
                              void* d_out, int out_size, void* d_ws, size_t ws_size,
                              hipStream_t stream) {
    const float* queries = (const float*)d_in[0];
    const float* keys    = (const float*)d_in[1];
    const float* values  = (const float*)d_in[2];
    const float* tK      = (const float*)d_in[3];
    const float* tV      = (const float*)d_in[4];
    const float* apK     = (const float*)d_in[5];
    const float* apV     = (const float*)d_in[6];
    const int*   tmask   = (const int*)d_in[7];
    // d_in[8] future_time_mask: analytic (k > q), never read
    const float* Wq = (const float*)d_in[9];
    const float* bq = (const float*)d_in[10];
    const float* Wk = (const float*)d_in[11];
    const float* bk = (const float*)d_in[12];
    const float* Wv = (const float*)d_in[13];
    const float* bv = (const float*)d_in[14];

    float* ws = (float*)d_ws;
    float* Qo     = ws;                     // [1024][256]
    float* Ko     = ws + 262144;            // Keff = K + bk + pK
    float* Vo     = ws + 524288;            // Veff = V + bv + pV
    float* scores = ws + 786432;            // [1024*4][256]
    float* partb  = ws + 1835008;           // [4][1024][256]
    float* out = (float*)d_out;

    proj_kernel<<<256, 256, 0, stream>>>(queries, keys, values, apK, apV,
                                         Wq, bq, Wk, bk, Wv, bv, Qo, Ko, Vo);
    scores_kernel<<<4096, 256, 0, stream>>>(Qo, Ko, tK, tmask, scores);
    softmax_kernel<<<1024, 256, 0, stream>>>(scores, tmask);
    pv_kernel<<<4096, 256, 0, stream>>>(Vo, tV, scores, tmask, partb);
    reduce_kernel<<<1024, 256, 0, stream>>>(partb, tmask, out);
}